// Round 6
// baseline (2068.737 us; speedup 1.0000x reference)
//
#include <hip/hip_runtime.h>
#include <hip/hip_bf16.h>
#include <hip/hip_cooperative_groups.h>

namespace cg = cooperative_groups;

#define N_NODES_DIM0 128

typedef unsigned short u16;
typedef unsigned int u32;
typedef __attribute__((ext_vector_type(8))) short short8;
typedef __attribute__((ext_vector_type(4))) float f32x4;

__device__ __forceinline__ float bf2f(u16 h) { return __uint_as_float((u32)h << 16); }
__device__ __forceinline__ u16 f2bf(float f) {
    u32 u = __float_as_uint(f);
    u32 r = (u + 0x7FFFu + ((u >> 16) & 1u)) >> 16;  // round-to-nearest-even
    return (u16)r;
}

// async global->LDS, 16 B per lane; lds dest = wave-uniform base + lane*16
__device__ __forceinline__ void gl2lds16(const u16* g, u16* lds_base) {
    __builtin_amdgcn_global_load_lds(
        (const __attribute__((address_space(1))) u32*)g,
        (__attribute__((address_space(3))) u32*)lds_base, 16, 0, 0);
}

// ---------------- CSR build (scan-free: wave-scan + atomic bump allocator) ----------------

// merged: histogram + LDS-tiled weight transpose-cast (independent work, one node)
__global__ __launch_bounds__(256) void hist_wt_kernel(
    const int* __restrict__ dst, int* __restrict__ cnt, int e, int histB,
    const float* __restrict__ W0, const float* __restrict__ W1,
    const float* __restrict__ W2, const float* __restrict__ W3, u16* __restrict__ Wt) {
    __shared__ float tile[32][33];
    int bid = blockIdx.x;
    if (bid < histB) {
        int i = bid * 256 + threadIdx.x;
        if (i < e) atomicAdd(&cnt[dst[i]], 1);
        return;
    }
    bid -= histB;  // 0..783 W-transpose blocks
    const float* W; u16* out; int K, F, kb, nb;
    if (bid < 128)      { W = W0; out = Wt;          K = 128;  F = 1024; kb = bid & 3;  nb = bid >> 2; }
    else if (bid < 640) { int l = bid - 128; W = W1; out = Wt + 131072; K = 1024; F = 512; kb = l & 31; nb = l >> 5; }
    else if (bid < 768) { int l = bid - 640; W = W2; out = Wt + 655360; K = 512;  F = 256; kb = l & 15; nb = l >> 4; }
    else                { int l = bid - 768; W = W3; out = Wt + 786432; K = 256;  F = 64;  kb = l & 7;  nb = l >> 3; }
    int k0 = kb * 32, n0 = nb * 32;
    int tx = threadIdx.x & 31, ty = threadIdx.x >> 5;
#pragma unroll
    for (int i = 0; i < 4; ++i) {
        int k = ty + i * 8;
        tile[k][tx] = W[(size_t)(k0 + k) * F + n0 + tx];  // coalesced 128B rows
    }
    __syncthreads();
#pragma unroll
    for (int i = 0; i < 4; ++i) {
        int n = ty + i * 8;
        out[(size_t)(n0 + n) * K + k0 + tx] = f2bf(tile[tx][n]);  // coalesced bf16 rows
    }
}

__global__ void alloc_kernel(const int* __restrict__ cnt, int* __restrict__ row_start,
                             float* __restrict__ dinv, int* __restrict__ cursor, int n) {
    int i = blockIdx.x * blockDim.x + threadIdx.x;
    int lane = threadIdx.x & 63;
    int v = (i < n) ? cnt[i] : 0;
    int s = v;  // inclusive wave prefix
#pragma unroll
    for (int off = 1; off < 64; off <<= 1) {
        int x = __shfl_up(s, off, 64);
        if (lane >= off) s += x;
    }
    int total = __shfl(s, 63, 64);
    int base = 0;
    if (lane == 0) base = atomicAdd(cursor, total);
    base = __shfl(base, 0, 64);
    if (i < n) {
        row_start[i] = base + s - v;  // exclusive within wave
        dinv[i] = rsqrtf((float)v + 1.0f);
    }
}

// merged: CSR bump-fill + input scale-cast (both depend only on alloc; one node)
__global__ __launch_bounds__(256) void fill_y_kernel(
    const int* __restrict__ src, const int* __restrict__ dst,
    int* __restrict__ row_start, int* __restrict__ csr_src, int e, int fillB,
    const float* __restrict__ x, const float* __restrict__ dinv,
    u16* __restrict__ Y, int N) {
    int bid = blockIdx.x;
    if (bid < fillB) {
        int i = bid * 256 + threadIdx.x;
        if (i < e) {
            int d = dst[i];
            int pos = atomicAdd(&row_start[d], 1);
            csr_src[pos] = src[i];
        }
        return;
    }
    int gid = (bid - fillB) * 256 + threadIdx.x;
    int node = gid >> 5;
    int c4 = (gid & 31) * 4;
    if (node >= N) return;
    float dv = dinv[node];
    float4 v = *reinterpret_cast<const float4*>(x + (size_t)node * 128 + c4);
    ushort4 r;
    r.x = f2bf(dv * v.x); r.y = f2bf(dv * v.y);
    r.z = f2bf(dv * v.z); r.w = f2bf(dv * v.w);
    *reinterpret_cast<ushort4*>(Y + (size_t)node * 128 + c4) = r;
}

// ---------------- helpers: bf16x8 accumulate ----------------
__device__ __forceinline__ void add8v(float* acc, short8 v) {
#pragma unroll
    for (int w = 0; w < 8; ++w) acc[w] += bf2f((u16)v[w]);
}
__device__ __forceinline__ void add16p(float* acc, const u16* p) {
    short8 a = *reinterpret_cast<const short8*>(p);
    short8 b = *reinterpret_cast<const short8*>(p + 8);
    add8v(acc, a); add8v(acc + 8, b);
}

// 16-channel CSR gather-accumulate. R0/R1/R4 verdict: pinned at ~3.9-4.0 TB/s memory
// service rate regardless of MLP depth, occupancy, or store policy -> only overhead
// removal (fewer nodes) helps at the pipeline level.
__device__ __forceinline__ void gather_sum16(float* acc, const u16* __restrict__ base,
                                             const int* __restrict__ csr_src,
                                             int beg, int end, int stride, int ch) {
    int e = beg;
    int nfull = (end - beg) >> 3;
    if (nfull > 0) {
        int i0 = csr_src[e],     i1 = csr_src[e + 1], i2 = csr_src[e + 2], i3 = csr_src[e + 3];
        int i4 = csr_src[e + 4], i5 = csr_src[e + 5], i6 = csr_src[e + 6], i7 = csr_src[e + 7];
        for (int b = 0; b < nfull; ++b) {
            const u16* p0 = base + (size_t)i0 * stride + ch;
            const u16* p1 = base + (size_t)i1 * stride + ch;
            const u16* p2 = base + (size_t)i2 * stride + ch;
            const u16* p3 = base + (size_t)i3 * stride + ch;
            const u16* p4 = base + (size_t)i4 * stride + ch;
            const u16* p5 = base + (size_t)i5 * stride + ch;
            const u16* p6 = base + (size_t)i6 * stride + ch;
            const u16* p7 = base + (size_t)i7 * stride + ch;
            short8 a0 = *reinterpret_cast<const short8*>(p0), b0 = *reinterpret_cast<const short8*>(p0 + 8);
            short8 a1 = *reinterpret_cast<const short8*>(p1), b1 = *reinterpret_cast<const short8*>(p1 + 8);
            short8 a2 = *reinterpret_cast<const short8*>(p2), b2 = *reinterpret_cast<const short8*>(p2 + 8);
            short8 a3 = *reinterpret_cast<const short8*>(p3), b3 = *reinterpret_cast<const short8*>(p3 + 8);
            short8 a4 = *reinterpret_cast<const short8*>(p4), b4 = *reinterpret_cast<const short8*>(p4 + 8);
            short8 a5 = *reinterpret_cast<const short8*>(p5), b5 = *reinterpret_cast<const short8*>(p5 + 8);
            short8 a6 = *reinterpret_cast<const short8*>(p6), b6 = *reinterpret_cast<const short8*>(p6 + 8);
            short8 a7 = *reinterpret_cast<const short8*>(p7), b7 = *reinterpret_cast<const short8*>(p7 + 8);
            e += 8;
            int ep = (e + 8 <= end) ? e : beg;
            i0 = csr_src[ep];     i1 = csr_src[ep + 1]; i2 = csr_src[ep + 2]; i3 = csr_src[ep + 3];
            i4 = csr_src[ep + 4]; i5 = csr_src[ep + 5]; i6 = csr_src[ep + 6]; i7 = csr_src[ep + 7];
            __builtin_amdgcn_sched_barrier(0);
            add8v(acc, a0); add8v(acc + 8, b0);
            add8v(acc, a1); add8v(acc + 8, b1);
            add8v(acc, a2); add8v(acc + 8, b2);
            add8v(acc, a3); add8v(acc + 8, b3);
            add8v(acc, a4); add8v(acc + 8, b4);
            add8v(acc, a5); add8v(acc + 8, b5);
            add8v(acc, a6); add8v(acc + 8, b6);
            add8v(acc, a7); add8v(acc + 8, b7);
        }
    }
    for (; e + 4 <= end; e += 4) {
        const u16* p0 = base + (size_t)csr_src[e]     * stride + ch;
        const u16* p1 = base + (size_t)csr_src[e + 1] * stride + ch;
        const u16* p2 = base + (size_t)csr_src[e + 2] * stride + ch;
        const u16* p3 = base + (size_t)csr_src[e + 3] * stride + ch;
        short8 a0 = *reinterpret_cast<const short8*>(p0), b0 = *reinterpret_cast<const short8*>(p0 + 8);
        short8 a1 = *reinterpret_cast<const short8*>(p1), b1 = *reinterpret_cast<const short8*>(p1 + 8);
        short8 a2 = *reinterpret_cast<const short8*>(p2), b2 = *reinterpret_cast<const short8*>(p2 + 8);
        short8 a3 = *reinterpret_cast<const short8*>(p3), b3 = *reinterpret_cast<const short8*>(p3 + 8);
        __builtin_amdgcn_sched_barrier(0);
        add8v(acc, a0); add8v(acc + 8, b0);
        add8v(acc, a1); add8v(acc + 8, b1);
        add8v(acc, a2); add8v(acc + 8, b2);
        add8v(acc, a3); add8v(acc + 8, b3);
    }
    for (; e < end; ++e) {
        const u16* p = base + (size_t)csr_src[e] * stride + ch;
        short8 a = *reinterpret_cast<const short8*>(p), b = *reinterpret_cast<const short8*>(p + 8);
        add8v(acc, a); add8v(acc + 8, b);
    }
}

// ---------------- aggregation bodies (gid-indexed; exact R4 arithmetic) ----------------
// MODE 0: out = bf16(dinv*acc)   MODE 1: out = bf16(relu(fma(dinv, acc, bias)))
template <int MODE>
__device__ __forceinline__ void agg_gid(int gid, const int* __restrict__ row_end,
        const int* __restrict__ cnt, const int* __restrict__ csr_src,
        const u16* __restrict__ Gin, const float* __restrict__ dinv,
        const float* __restrict__ bias, u16* __restrict__ XO, int F, int lgG) {
    int node = gid >> lgG;
    int ch = (gid & ((1 << lgG) - 1)) * 16;
    float acc[16] = {};
    add16p(acc, Gin + (size_t)node * F + ch);  // self-loop
    int end = row_end[node], beg = end - cnt[node];
    gather_sum16(acc, Gin, csr_src, beg, end, F, ch);
    float dv = dinv[node];
    short8 r0, r1;
#pragma unroll
    for (int w = 0; w < 8; ++w) {
        if (MODE == 0) {
            r0[w] = (short)f2bf(dv * acc[w]);
            r1[w] = (short)f2bf(dv * acc[8 + w]);
        } else {
            r0[w] = (short)f2bf(fmaxf(fmaf(dv, acc[w], bias[ch + w]), 0.f));
            r1[w] = (short)f2bf(fmaxf(fmaf(dv, acc[8 + w], bias[ch + 8 + w]), 0.f));
        }
    }
    *reinterpret_cast<short8*>(XO + (size_t)node * F + ch) = r0;
    *reinterpret_cast<short8*>(XO + (size_t)node * F + ch + 8) = r1;
}

// fused layer-4 aggregation + layer-5 dot (4 thr/node, 16 ch each)
__device__ __forceinline__ void l5_gid(int gid, const int* __restrict__ row_end,
        const int* __restrict__ cnt, const int* __restrict__ csr_src,
        const u16* __restrict__ Gc, const float* __restrict__ dinv,
        const float* __restrict__ b4, const float* __restrict__ W5,
        float* __restrict__ g5) {
    int node = gid >> 2;
    int ch = (gid & 3) * 16;
    float acc[16] = {};
    add16p(acc, Gc + (size_t)node * 64 + ch);  // self-loop
    int end = row_end[node], beg = end - cnt[node];
    gather_sum16(acc, Gc, csr_src, beg, end, 64, ch);
    float dv = dinv[node];
    float dot = 0.f;
#pragma unroll
    for (int w = 0; w < 16; ++w) {
        float v = fmaxf(fmaf(dv, acc[w], b4[ch + w]), 0.f);  // fp32 activation
        dot = fmaf(v, W5[ch + w], dot);
    }
#pragma unroll
    for (int off = 2; off > 0; off >>= 1) dot += __shfl_down(dot, off, 4);
    if ((gid & 3) == 0) g5[node] = dv * dot;
}

__device__ __forceinline__ void agg5_gid(int i, const int* __restrict__ row_end,
        const int* __restrict__ cnt, const int* __restrict__ csr_src,
        const float* __restrict__ g5, const float* __restrict__ dinv,
        const float* __restrict__ b5, float* __restrict__ out) {
    float acc = g5[i];
    int end = row_end[i], e = end - cnt[i];
    for (; e + 4 <= end; e += 4) {
        float a = g5[csr_src[e]];
        float b = g5[csr_src[e + 1]];
        float c = g5[csr_src[e + 2]];
        float d = g5[csr_src[e + 3]];
        acc += (a + b) + (c + d);
    }
    for (; e < end; ++e) acc += g5[csr_src[e]];
    out[i] = fmaxf(fmaf(dinv[i], acc, b5[0]), 0.f);
}

// ---------------- MFMA bf16 GEMM tile body (rb,cb addressed; exact R4 inner loop) --------
// EPI=0: Out = bf16(dinv[row] * acc)     EPI=1: Out = bf16(relu(acc + bias[col]))
template <int BN, int TPB, int EPI>
__device__ __forceinline__ void gemm_tile(
    u16* As, u16* Bs, int rb, int cb, int t,
    const u16* X, const u16* __restrict__ Wt,
    const float* __restrict__ dinv, const float* __restrict__ bias,
    u16* Out, int N, int K, int F) {
    constexpr int BM = 128, BK = 64;
    constexpr int RA = (BM * 8) / TPB;
    constexpr int RB = (BN * 8) / TPB;
    constexpr int WAVES = TPB / 64;
    constexpr int WAVES_N = (BN >= 64) ? (BN / 64) : 1;
    constexpr int WAVES_M = WAVES / WAVES_N;
    constexpr int WM = BM / WAVES_M;
    constexpr int WN = BN / WAVES_N;
    constexpr int NI = WM / 16;
    constexpr int NJ = WN / 16;

    const int wave = t >> 6;
    const int lane = t & 63;
    const int m16 = lane & 15;
    const int quad = lane >> 4;

    const int row0 = rb * BM;
    const int col0 = cb * BN;

    const int wm = (wave / WAVES_N) * WM;
    const int wn = (wave % WAVES_N) * WN;

    const u16* aSrc[RA];
    u16* aDst[RA];
#pragma unroll
    for (int rr = 0; rr < RA; ++rr) {
        int c = rr * TPB + t;
        int r = c >> 3;
        int q = (c ^ r) & 7;  // XOR swizzle
        int grow = row0 + r;
        if (grow >= N) grow = 0;  // clamped rows feed only epilogue-guarded outputs
        aSrc[rr] = X + (size_t)grow * K + q * 8;
        aDst[rr] = &As[(size_t)(rr * TPB + wave * 64) * 8];
    }
    const u16* bSrc[RB];
    u16* bDst[RB];
#pragma unroll
    for (int rr = 0; rr < RB; ++rr) {
        int c = rr * TPB + t;
        int r = c >> 3;
        int q = (c ^ r) & 7;
        bSrc[rr] = Wt + (size_t)(col0 + r) * K + q * 8;
        bDst[rr] = &Bs[(size_t)(rr * TPB + wave * 64) * 8];
    }

    u32 aOff[NI][2], bOff[NJ][2];
#pragma unroll
    for (int i = 0; i < NI; ++i)
#pragma unroll
        for (int h = 0; h < 2; ++h) {
            int row = wm + i * 16 + m16;
            int qg = h * 4 + quad;
            aOff[i][h] = (u32)(((row << 3) | ((qg ^ row) & 7)) * 16);
        }
#pragma unroll
    for (int j = 0; j < NJ; ++j)
#pragma unroll
        for (int h = 0; h < 2; ++h) {
            int row = wn + j * 16 + m16;
            int qg = h * 4 + quad;
            bOff[j][h] = (u32)(((row << 3) | ((qg ^ row) & 7)) * 16);
        }
    const char* AsB = reinterpret_cast<const char*>(As);
    const char* BsB = reinterpret_cast<const char*>(Bs);

    f32x4 acc[NI][NJ] = {};

    for (int k0 = 0; k0 < K; k0 += BK) {
#pragma unroll
        for (int rr = 0; rr < RA; ++rr) {
            gl2lds16(aSrc[rr], aDst[rr]);
            aSrc[rr] += BK;
        }
#pragma unroll
        for (int rr = 0; rr < RB; ++rr) {
            gl2lds16(bSrc[rr], bDst[rr]);
            bSrc[rr] += BK;
        }
        __syncthreads();  // drains vmcnt -> LDS valid

#pragma unroll
        for (int h = 0; h < 2; ++h) {
            short8 af[NI], bf[NJ];
#pragma unroll
            for (int i = 0; i < NI; ++i)
                af[i] = *reinterpret_cast<const short8*>(AsB + aOff[i][h]);
#pragma unroll
            for (int j = 0; j < NJ; ++j)
                bf[j] = *reinterpret_cast<const short8*>(BsB + bOff[j][h]);
#pragma unroll
            for (int i = 0; i < NI; ++i)
#pragma unroll
                for (int j = 0; j < NJ; ++j)
                    acc[i][j] = __builtin_amdgcn_mfma_f32_16x16x32_bf16(af[i], bf[j], acc[i][j], 0, 0, 0);
        }
        __syncthreads();
    }

    // epilogue: C/D layout col=lane&15, row=quad*4+reg  [measured m89/m91]
#pragma unroll
    for (int i = 0; i < NI; ++i) {
#pragma unroll
        for (int r = 0; r < 4; ++r) {
            int grow = row0 + wm + i * 16 + quad * 4 + r;
            if (grow >= N) continue;
            float dv = (EPI == 0) ? dinv[grow] : 0.f;
#pragma unroll
            for (int j = 0; j < NJ; ++j) {
                int gcol = col0 + wn + j * 16 + m16;
                float v = acc[i][j][r];
                if (EPI == 0) v = dv * v;
                else          v = fmaxf(v + bias[gcol], 0.f);
                Out[(size_t)grow * F + gcol] = f2bf(v);
            }
        }
    }
}

// ---------------- standalone wrappers (serial fallback path) ----------------
template <int MODE>
__global__ __launch_bounds__(256, 4) void agg_k(
        const int* __restrict__ re, const int* __restrict__ cnt, const int* __restrict__ csr,
        const u16* __restrict__ Gin, const float* __restrict__ dinv,
        const float* __restrict__ bias, u16* __restrict__ XO, int total, int F, int lgG) {
    int gid = blockIdx.x * 256 + threadIdx.x;
    if (gid < total) agg_gid<MODE>(gid, re, cnt, csr, Gin, dinv, bias, XO, F, lgG);
}

template <int BN, int TPB, int EPI>
__global__ __launch_bounds__(TPB) void gemm_k(
        const u16* X, const u16* __restrict__ Wt, const float* __restrict__ dinv,
        const float* __restrict__ bias, u16* Out, int N, int K, int F, int nx) {
    __shared__ u16 As[128 * 64];
    __shared__ u16 Bs[BN * 64];
    int tile = blockIdx.x;
    gemm_tile<BN, TPB, EPI>(As, Bs, tile / nx, tile % nx, threadIdx.x,
                            X, Wt, dinv, bias, Out, N, K, F);
}

__global__ __launch_bounds__(256, 4) void l5_k(
        const int* __restrict__ re, const int* __restrict__ cnt, const int* __restrict__ csr,
        const u16* __restrict__ Gc, const float* __restrict__ dinv,
        const float* __restrict__ b4, const float* __restrict__ W5,
        float* __restrict__ g5, int total) {
    int gid = blockIdx.x * 256 + threadIdx.x;
    if (gid < total) l5_gid(gid, re, cnt, csr, Gc, dinv, b4, W5, g5);
}

__global__ void agg5_k(const int* __restrict__ re, const int* __restrict__ cnt,
                       const int* __restrict__ csr, const float* __restrict__ g5,
                       const float* __restrict__ dinv, const float* __restrict__ b5,
                       float* __restrict__ out, int N) {
    int i = blockIdx.x * blockDim.x + threadIdx.x;
    if (i < N) agg5_gid(i, re, cnt, csr, g5, dinv, b5, out);
}

// ---------------- cooperative mega-kernel: 9 layer dispatches -> 1 node ----------------
// Rationale: component-sum (~276 us) vs wall (416 us) implies ~10 us/dispatch-node
// overhead (R5's +27 us for +3 launches corroborates). All stage bodies identical to
// the proven serial kernels; stages separated by grid.sync(). 768 blocks x 512 thr,
// bounds (512,6): VGPR<=85 (standalone bodies measured 60-64), LDS 48KB -> 3 blocks/CU
// guaranteed co-residency.
struct MegaP {
    const int* rstart; const int* cnt; const int* csr;
    const u16* Y; u16* Z; u16* Gc; u16* XA; u16* XB;
    const float* dinv;
    const u16* Wt0; const u16* Wt1; const u16* Wt2; const u16* Wt3;
    const float* bias1024; const float* bias512; const float* bias256;
    const float* bias64; const float* bias1;
    const float* W5;
    float* g5; float* out;
    int N; int ny;
};

__global__ __launch_bounds__(512, 6) void mega_kernel(MegaP P) {
    __shared__ u16 As[128 * 64];   // 16 KB
    __shared__ u16 Bs[256 * 64];   // 32 KB
    cg::grid_group grid = cg::this_grid();
    const int t = threadIdx.x;
    const int nb = (int)gridDim.x;
    const int tstride = nb * 512;
    const int N = P.N, ny = P.ny;

    // s0: layer-1 pre-agg  Y -> Z   (F=128, 8 thr/node)
    for (int gid = blockIdx.x * 512 + t, tot = N << 3; gid < tot; gid += tstride)
        agg_gid<0>(gid, P.rstart, P.cnt, P.csr, P.Y, P.dinv, nullptr, P.Z, 128, 3);
    grid.sync();

    // s1: gemm1  Z @ W1 -> XA  (K=128, F=1024, EPI=1), rb-major tiles for L2 A-reuse
    for (int tile = blockIdx.x, nt = ny * 4; tile < nt; tile += nb) {
        gemm_tile<256, 512, 1>(As, Bs, tile >> 2, tile & 3, t,
                               P.Z, P.Wt0, P.dinv, P.bias1024, P.XA, N, 128, 1024);
        __syncthreads();
    }
    grid.sync();

    // s2: gemm2  XA @ W2 -> Gc512  (K=1024, F=512, EPI=0)
    for (int tile = blockIdx.x, nt = ny * 2; tile < nt; tile += nb) {
        gemm_tile<256, 512, 0>(As, Bs, tile >> 1, tile & 1, t,
                               P.XA, P.Wt1, P.dinv, P.bias512, P.Gc, N, 1024, 512);
        __syncthreads();
    }
    grid.sync();

    // s3: agg2  Gc512 -> XB  (F=512, 32 thr/node, bias b2 + relu)
    for (int gid = blockIdx.x * 512 + t, tot = N << 5; gid < tot; gid += tstride)
        agg_gid<1>(gid, P.rstart, P.cnt, P.csr, P.Gc, P.dinv, P.bias512, P.XB, 512, 5);
    grid.sync();

    // s4: gemm3  XB @ W3 -> Gc256  (K=512, F=256, EPI=0)
    for (int tile = blockIdx.x; tile < ny; tile += nb) {
        gemm_tile<256, 512, 0>(As, Bs, tile, 0, t,
                               P.XB, P.Wt2, P.dinv, P.bias256, P.Gc, N, 512, 256);
        __syncthreads();
    }
    grid.sync();

    // s5: agg3  Gc256 -> XA  (F=256, 16 thr/node, bias b3 + relu)
    for (int gid = blockIdx.x * 512 + t, tot = N << 4; gid < tot; gid += tstride)
        agg_gid<1>(gid, P.rstart, P.cnt, P.csr, P.Gc, P.dinv, P.bias256, P.XA, 256, 4);
    grid.sync();

    // s6: gemm4  XA @ W4 -> Gc64  (K=256, F=64, EPI=0)
    for (int tile = blockIdx.x; tile < ny; tile += nb) {
        gemm_tile<64, 512, 0>(As, Bs, tile, 0, t,
                              P.XA, P.Wt3, P.dinv, P.bias64, P.Gc, N, 256, 64);
        __syncthreads();
    }
    grid.sync();

    // s7: fused layer-4 agg + layer-5 dot  Gc64 -> g5
    for (int gid = blockIdx.x * 512 + t, tot = N << 2; gid < tot; gid += tstride)
        l5_gid(gid, P.rstart, P.cnt, P.csr, P.Gc, P.dinv, P.bias64, P.W5, P.g5);
    grid.sync();

    // s8: layer-5 aggregation  g5 -> out
    for (int i = blockIdx.x * 512 + t; i < N; i += tstride)
        agg5_gid(i, P.rstart, P.cnt, P.csr, P.g5, P.dinv, P.bias1, P.out);
}

// ---------------- launch ----------------

static inline size_t align_up(size_t x) { return (x + 255) & ~(size_t)255; }

extern "C" void kernel_launch(void* const* d_in, const int* in_sizes, int n_in,
                              void* d_out, int out_size, void* d_ws, size_t ws_size,
                              hipStream_t stream) {
    const float* x  = (const float*)d_in[0];
    const int*   ei = (const int*)d_in[1];
    const int E = in_sizes[1] / 2;
    const int N = in_sizes[0] / N_NODES_DIM0;
    const int* src = ei;
    const int* dst = ei + E;

    const float* W[5] = {(const float*)d_in[2], (const float*)d_in[4], (const float*)d_in[6],
                         (const float*)d_in[8], (const float*)d_in[10]};
    const float* B[5] = {(const float*)d_in[3], (const float*)d_in[5], (const float*)d_in[7],
                         (const float*)d_in[9], (const float*)d_in[11]};

    const int Ks[4] = {128, 1024, 512, 256};
    const int Fs[4] = {1024, 512, 256, 64};

    // workspace carve — peak ~209 MB
    char* w = (char*)d_ws;
    size_t off = 0;
    float* dinv    = (float*)(w + off); off += align_up((size_t)N * 4);
    float* g5      = (float*)(w + off); off += align_up((size_t)N * 4);
    int*   cnt     = (int*)(w + off);   off += align_up((size_t)(N + 1) * 4);  // cnt[N] = cursor
    int*   rstart  = (int*)(w + off);   off += align_up((size_t)N * 4);        // bump ptr -> row end
    int*   csr_src = (int*)(w + off);   off += align_up((size_t)E * 4);        // 1.6 MB
    u16* WtBase = (u16*)(w + off);
    u16* Wt[4];
    {
        size_t cum = 0;
        for (int l = 0; l < 4; ++l) {
            Wt[l] = WtBase + cum;
            cum += (size_t)Ks[l] * Fs[l];
        }
        off += align_up(cum * 2);
    }
    char* REG = w + off;               off += align_up((size_t)N * 512 * 2);    // 51.2 MB
    u16* Y  = (u16*)REG;
    u16* Z  = (u16*)(REG + align_up((size_t)N * 128 * 2));
    u16* Gc = (u16*)REG;               // 512/256/64-wide GEMM outputs (sequenced reuse)
    u16* XA = (u16*)(w + off);         off += align_up((size_t)N * 1024 * 2);   // 102.4 MB
    u16* XB = (u16*)(w + off);         off += align_up((size_t)N * 512 * 2);    // 51.2 MB
    (void)ws_size;

    // ---- setup: 4 nodes ----
    hipMemsetAsync(cnt, 0, (size_t)(N + 1) * 4, stream);
    {
        int histB = (E + 255) / 256;
        hist_wt_kernel<<<histB + 784, 256, 0, stream>>>(dst, cnt, E, histB,
                                                        W[0], W[1], W[2], W[3], WtBase);
    }
    alloc_kernel<<<(N + 255) / 256, 256, 0, stream>>>(cnt, rstart, dinv, &cnt[N], N);
    {
        int fillB = (E + 255) / 256;
        int yB = (N * 32 + 255) / 256;
        fill_y_kernel<<<fillB + yB, 256, 0, stream>>>(src, dst, rstart, csr_src, E, fillB,
                                                      x, dinv, Y, N);
    }

    const int ny = (N + 127) / 128;

    // ---- all 9 layer stages: one cooperative node ----
    MegaP P;
    P.rstart = rstart; P.cnt = cnt; P.csr = csr_src;
    P.Y = Y; P.Z = Z; P.Gc = Gc; P.XA = XA; P.XB = XB;
    P.dinv = dinv;
    P.Wt0 = Wt[0]; P.Wt1 = Wt[1]; P.Wt2 = Wt[2]; P.Wt3 = Wt[3];
    P.bias1024 = B[0]; P.bias512 = B[1]; P.bias256 = B[2]; P.bias64 = B[3]; P.bias1 = B[4];
    P.W5 = W[4];
    P.g5 = g5; P.out = (float*)d_out;
    P.N = N; P.ny = ny;

    void* args[] = { &P };
    hipError_t err = hipLaunchCooperativeKernel((const void*)mega_kernel,
                                                dim3(768), dim3(512), args, 0, stream);
    if (err != hipSuccess) {
        (void)hipGetLastError();  // clear sticky error; serial fallback (R4 pipeline)
        agg_k<0><<<(N * 8 + 255) / 256, 256, 0, stream>>>(
            rstart, cnt, csr_src, Y, dinv, nullptr, Z, N * 8, 128, 3);
        gemm_k<256, 512, 1><<<ny * 4, 512, 0, stream>>>(Z, Wt[0], dinv, B[0], XA,
                                                        N, 128, 1024, 4);
        gemm_k<256, 512, 0><<<ny * 2, 512, 0, stream>>>(XA, Wt[1], dinv, B[1], Gc,
                                                        N, 1024, 512, 2);
        agg_k<1><<<(N * 32 + 255) / 256, 256, 0, stream>>>(
            rstart, cnt, csr_src, Gc, dinv, B[1], XB, N * 32, 512, 5);
        gemm_k<256, 512, 0><<<ny, 512, 0, stream>>>(XB, Wt[2], dinv, B[2], Gc,
                                                    N, 512, 256, 1);
        agg_k<1><<<(N * 16 + 255) / 256, 256, 0, stream>>>(
            rstart, cnt, csr_src, Gc, dinv, B[2], XA, N * 16, 256, 4);
        gemm_k<64, 512, 0><<<ny, 512, 0, stream>>>(XA, Wt[3], dinv, B[3], Gc,
                                                   N, 256, 64, 1);
        l5_k<<<(N * 4 + 255) / 256, 256, 0, stream>>>(rstart, cnt, csr_src, Gc, dinv,
                                                      B[3], W[4], g5, N * 4);
        agg5_k<<<(N + 255) / 256, 256, 0, stream>>>(rstart, cnt, csr_src, g5, dinv,
                                                    B[4], (float*)d_out, N);
    }
}

// Round 7
// 424.958 us; speedup vs baseline: 4.8681x; 4.8681x over previous
//
#include <hip/hip_runtime.h>
#include <hip/hip_bf16.h>
#include <hip/hip_cooperative_groups.h>

namespace cg = cooperative_groups;

#define N_NODES_DIM0 128

typedef unsigned short u16;
typedef unsigned int u32;
typedef __attribute__((ext_vector_type(8))) short short8;
typedef __attribute__((ext_vector_type(4))) float f32x4;

__device__ __forceinline__ float bf2f(u16 h) { return __uint_as_float((u32)h << 16); }
__device__ __forceinline__ u16 f2bf(float f) {
    u32 u = __float_as_uint(f);
    u32 r = (u + 0x7FFFu + ((u >> 16) & 1u)) >> 16;  // round-to-nearest-even
    return (u16)r;
}

// async global->LDS, 16 B per lane; lds dest = wave-uniform base + lane*16
__device__ __forceinline__ void gl2lds16(const u16* g, u16* lds_base) {
    __builtin_amdgcn_global_load_lds(
        (const __attribute__((address_space(1))) u32*)g,
        (__attribute__((address_space(3))) u32*)lds_base, 16, 0, 0);
}

// ---------------- CSR build (scan-free: wave-scan + atomic bump allocator) ----------------

// merged: histogram + LDS-tiled weight transpose-cast (independent work, one node)
__global__ __launch_bounds__(256) void hist_wt_kernel(
    const int* __restrict__ dst, int* __restrict__ cnt, int e, int histB,
    const float* __restrict__ W0, const float* __restrict__ W1,
    const float* __restrict__ W2, const float* __restrict__ W3, u16* __restrict__ Wt) {
    __shared__ float tile[32][33];
    int bid = blockIdx.x;
    if (bid < histB) {
        int i = bid * 256 + threadIdx.x;
        if (i < e) atomicAdd(&cnt[dst[i]], 1);
        return;
    }
    bid -= histB;  // 0..783 W-transpose blocks
    const float* W; u16* out; int K, F, kb, nb;
    if (bid < 128)      { W = W0; out = Wt;          K = 128;  F = 1024; kb = bid & 3;  nb = bid >> 2; }
    else if (bid < 640) { int l = bid - 128; W = W1; out = Wt + 131072; K = 1024; F = 512; kb = l & 31; nb = l >> 5; }
    else if (bid < 768) { int l = bid - 640; W = W2; out = Wt + 655360; K = 512;  F = 256; kb = l & 15; nb = l >> 4; }
    else                { int l = bid - 768; W = W3; out = Wt + 786432; K = 256;  F = 64;  kb = l & 7;  nb = l >> 3; }
    int k0 = kb * 32, n0 = nb * 32;
    int tx = threadIdx.x & 31, ty = threadIdx.x >> 5;
#pragma unroll
    for (int i = 0; i < 4; ++i) {
        int k = ty + i * 8;
        tile[k][tx] = W[(size_t)(k0 + k) * F + n0 + tx];  // coalesced 128B rows
    }
    __syncthreads();
#pragma unroll
    for (int i = 0; i < 4; ++i) {
        int n = ty + i * 8;
        out[(size_t)(n0 + n) * K + k0 + tx] = f2bf(tile[tx][n]);  // coalesced bf16 rows
    }
}

__global__ void alloc_kernel(const int* __restrict__ cnt, int* __restrict__ row_start,
                             float* __restrict__ dinv, int* __restrict__ cursor, int n) {
    int i = blockIdx.x * blockDim.x + threadIdx.x;
    int lane = threadIdx.x & 63;
    int v = (i < n) ? cnt[i] : 0;
    int s = v;  // inclusive wave prefix
#pragma unroll
    for (int off = 1; off < 64; off <<= 1) {
        int x = __shfl_up(s, off, 64);
        if (lane >= off) s += x;
    }
    int total = __shfl(s, 63, 64);
    int base = 0;
    if (lane == 0) base = atomicAdd(cursor, total);
    base = __shfl(base, 0, 64);
    if (i < n) {
        row_start[i] = base + s - v;  // exclusive within wave
        dinv[i] = rsqrtf((float)v + 1.0f);
    }
}

// merged: CSR bump-fill + input scale-cast (both depend only on alloc; one node)
__global__ __launch_bounds__(256) void fill_y_kernel(
    const int* __restrict__ src, const int* __restrict__ dst,
    int* __restrict__ row_start, int* __restrict__ csr_src, int e, int fillB,
    const float* __restrict__ x, const float* __restrict__ dinv,
    u16* __restrict__ Y, int N) {
    int bid = blockIdx.x;
    if (bid < fillB) {
        int i = bid * 256 + threadIdx.x;
        if (i < e) {
            int d = dst[i];
            int pos = atomicAdd(&row_start[d], 1);
            csr_src[pos] = src[i];
        }
        return;
    }
    int gid = (bid - fillB) * 256 + threadIdx.x;
    int node = gid >> 5;
    int c4 = (gid & 31) * 4;
    if (node >= N) return;
    float dv = dinv[node];
    float4 v = *reinterpret_cast<const float4*>(x + (size_t)node * 128 + c4);
    ushort4 r;
    r.x = f2bf(dv * v.x); r.y = f2bf(dv * v.y);
    r.z = f2bf(dv * v.z); r.w = f2bf(dv * v.w);
    *reinterpret_cast<ushort4*>(Y + (size_t)node * 128 + c4) = r;
}

// ---------------- helpers: bf16x8 accumulate ----------------
__device__ __forceinline__ void add8v(float* acc, short8 v) {
#pragma unroll
    for (int w = 0; w < 8; ++w) acc[w] += bf2f((u16)v[w]);
}
__device__ __forceinline__ void add16p(float* acc, const u16* p) {
    short8 a = *reinterpret_cast<const short8*>(p);
    short8 b = *reinterpret_cast<const short8*>(p + 8);
    add8v(acc, a); add8v(acc + 8, b);
}

// 16-channel CSR gather-accumulate (pinned at ~3.9-4.0 TB/s service rate; R0/R1/R4)
__device__ __forceinline__ void gather_sum16(float* acc, const u16* __restrict__ base,
                                             const int* __restrict__ csr_src,
                                             int beg, int end, int stride, int ch) {
    int e = beg;
    int nfull = (end - beg) >> 3;
    if (nfull > 0) {
        int i0 = csr_src[e],     i1 = csr_src[e + 1], i2 = csr_src[e + 2], i3 = csr_src[e + 3];
        int i4 = csr_src[e + 4], i5 = csr_src[e + 5], i6 = csr_src[e + 6], i7 = csr_src[e + 7];
        for (int b = 0; b < nfull; ++b) {
            const u16* p0 = base + (size_t)i0 * stride + ch;
            const u16* p1 = base + (size_t)i1 * stride + ch;
            const u16* p2 = base + (size_t)i2 * stride + ch;
            const u16* p3 = base + (size_t)i3 * stride + ch;
            const u16* p4 = base + (size_t)i4 * stride + ch;
            const u16* p5 = base + (size_t)i5 * stride + ch;
            const u16* p6 = base + (size_t)i6 * stride + ch;
            const u16* p7 = base + (size_t)i7 * stride + ch;
            short8 a0 = *reinterpret_cast<const short8*>(p0), b0 = *reinterpret_cast<const short8*>(p0 + 8);
            short8 a1 = *reinterpret_cast<const short8*>(p1), b1 = *reinterpret_cast<const short8*>(p1 + 8);
            short8 a2 = *reinterpret_cast<const short8*>(p2), b2 = *reinterpret_cast<const short8*>(p2 + 8);
            short8 a3 = *reinterpret_cast<const short8*>(p3), b3 = *reinterpret_cast<const short8*>(p3 + 8);
            short8 a4 = *reinterpret_cast<const short8*>(p4), b4 = *reinterpret_cast<const short8*>(p4 + 8);
            short8 a5 = *reinterpret_cast<const short8*>(p5), b5 = *reinterpret_cast<const short8*>(p5 + 8);
            short8 a6 = *reinterpret_cast<const short8*>(p6), b6 = *reinterpret_cast<const short8*>(p6 + 8);
            short8 a7 = *reinterpret_cast<const short8*>(p7), b7 = *reinterpret_cast<const short8*>(p7 + 8);
            e += 8;
            int ep = (e + 8 <= end) ? e : beg;
            i0 = csr_src[ep];     i1 = csr_src[ep + 1]; i2 = csr_src[ep + 2]; i3 = csr_src[ep + 3];
            i4 = csr_src[ep + 4]; i5 = csr_src[ep + 5]; i6 = csr_src[ep + 6]; i7 = csr_src[ep + 7];
            __builtin_amdgcn_sched_barrier(0);
            add8v(acc, a0); add8v(acc + 8, b0);
            add8v(acc, a1); add8v(acc + 8, b1);
            add8v(acc, a2); add8v(acc + 8, b2);
            add8v(acc, a3); add8v(acc + 8, b3);
            add8v(acc, a4); add8v(acc + 8, b4);
            add8v(acc, a5); add8v(acc + 8, b5);
            add8v(acc, a6); add8v(acc + 8, b6);
            add8v(acc, a7); add8v(acc + 8, b7);
        }
    }
    for (; e + 4 <= end; e += 4) {
        const u16* p0 = base + (size_t)csr_src[e]     * stride + ch;
        const u16* p1 = base + (size_t)csr_src[e + 1] * stride + ch;
        const u16* p2 = base + (size_t)csr_src[e + 2] * stride + ch;
        const u16* p3 = base + (size_t)csr_src[e + 3] * stride + ch;
        short8 a0 = *reinterpret_cast<const short8*>(p0), b0 = *reinterpret_cast<const short8*>(p0 + 8);
        short8 a1 = *reinterpret_cast<const short8*>(p1), b1 = *reinterpret_cast<const short8*>(p1 + 8);
        short8 a2 = *reinterpret_cast<const short8*>(p2), b2 = *reinterpret_cast<const short8*>(p2 + 8);
        short8 a3 = *reinterpret_cast<const short8*>(p3), b3 = *reinterpret_cast<const short8*>(p3 + 8);
        __builtin_amdgcn_sched_barrier(0);
        add8v(acc, a0); add8v(acc + 8, b0);
        add8v(acc, a1); add8v(acc + 8, b1);
        add8v(acc, a2); add8v(acc + 8, b2);
        add8v(acc, a3); add8v(acc + 8, b3);
    }
    for (; e < end; ++e) {
        const u16* p = base + (size_t)csr_src[e] * stride + ch;
        short8 a = *reinterpret_cast<const short8*>(p), b = *reinterpret_cast<const short8*>(p + 8);
        add8v(acc, a); add8v(acc + 8, b);
    }
}

// ---------------- aggregation bodies (gid-indexed) ----------------
template <int MODE>
__device__ __forceinline__ void agg_gid(int gid, const int* __restrict__ row_end,
        const int* __restrict__ cnt, const int* __restrict__ csr_src,
        const u16* __restrict__ Gin, const float* __restrict__ dinv,
        const float* __restrict__ bias, u16* __restrict__ XO, int F, int lgG) {
    int node = gid >> lgG;
    int ch = (gid & ((1 << lgG) - 1)) * 16;
    float acc[16] = {};
    add16p(acc, Gin + (size_t)node * F + ch);  // self-loop
    int end = row_end[node], beg = end - cnt[node];
    gather_sum16(acc, Gin, csr_src, beg, end, F, ch);
    float dv = dinv[node];
    short8 r0, r1;
#pragma unroll
    for (int w = 0; w < 8; ++w) {
        if (MODE == 0) {
            r0[w] = (short)f2bf(dv * acc[w]);
            r1[w] = (short)f2bf(dv * acc[8 + w]);
        } else {
            r0[w] = (short)f2bf(fmaxf(fmaf(dv, acc[w], bias[ch + w]), 0.f));
            r1[w] = (short)f2bf(fmaxf(fmaf(dv, acc[8 + w], bias[ch + 8 + w]), 0.f));
        }
    }
    *reinterpret_cast<short8*>(XO + (size_t)node * F + ch) = r0;
    *reinterpret_cast<short8*>(XO + (size_t)node * F + ch + 8) = r1;
}

__device__ __forceinline__ void l5_gid(int gid, const int* __restrict__ row_end,
        const int* __restrict__ cnt, const int* __restrict__ csr_src,
        const u16* __restrict__ Gc, const float* __restrict__ dinv,
        const float* __restrict__ b4, const float* __restrict__ W5,
        float* __restrict__ g5) {
    int node = gid >> 2;
    int ch = (gid & 3) * 16;
    float acc[16] = {};
    add16p(acc, Gc + (size_t)node * 64 + ch);  // self-loop
    int end = row_end[node], beg = end - cnt[node];
    gather_sum16(acc, Gc, csr_src, beg, end, 64, ch);
    float dv = dinv[node];
    float dot = 0.f;
#pragma unroll
    for (int w = 0; w < 16; ++w) {
        float v = fmaxf(fmaf(dv, acc[w], b4[ch + w]), 0.f);  // fp32 activation
        dot = fmaf(v, W5[ch + w], dot);
    }
#pragma unroll
    for (int off = 2; off > 0; off >>= 1) dot += __shfl_down(dot, off, 4);
    if ((gid & 3) == 0) g5[node] = dv * dot;
}

__device__ __forceinline__ void agg5_gid(int i, const int* __restrict__ row_end,
        const int* __restrict__ cnt, const int* __restrict__ csr_src,
        const float* __restrict__ g5, const float* __restrict__ dinv,
        const float* __restrict__ b5, float* __restrict__ out) {
    float acc = g5[i];
    int end = row_end[i], e = end - cnt[i];
    for (; e + 4 <= end; e += 4) {
        float a = g5[csr_src[e]];
        float b = g5[csr_src[e + 1]];
        float c = g5[csr_src[e + 2]];
        float d = g5[csr_src[e + 3]];
        acc += (a + b) + (c + d);
    }
    for (; e < end; ++e) acc += g5[csr_src[e]];
    out[i] = fmaxf(fmaf(dinv[i], acc, b5[0]), 0.f);
}

// ---------------- MFMA bf16 GEMM tile body (rb,cb addressed) ----------------
template <int BN, int TPB, int EPI>
__device__ __forceinline__ void gemm_tile(
    u16* As, u16* Bs, int rb, int cb, int t,
    const u16* X, const u16* __restrict__ Wt,
    const float* __restrict__ dinv, const float* __restrict__ bias,
    u16* Out, int N, int K, int F) {
    constexpr int BM = 128, BK = 64;
    constexpr int RA = (BM * 8) / TPB;
    constexpr int RB = (BN * 8) / TPB;
    constexpr int WAVES = TPB / 64;
    constexpr int WAVES_N = (BN >= 64) ? (BN / 64) : 1;
    constexpr int WAVES_M = WAVES / WAVES_N;
    constexpr int WM = BM / WAVES_M;
    constexpr int WN = BN / WAVES_N;
    constexpr int NI = WM / 16;
    constexpr int NJ = WN / 16;

    const int wave = t >> 6;
    const int lane = t & 63;
    const int m16 = lane & 15;
    const int quad = lane >> 4;

    const int row0 = rb * BM;
    const int col0 = cb * BN;

    const int wm = (wave / WAVES_N) * WM;
    const int wn = (wave % WAVES_N) * WN;

    const u16* aSrc[RA];
    u16* aDst[RA];
#pragma unroll
    for (int rr = 0; rr < RA; ++rr) {
        int c = rr * TPB + t;
        int r = c >> 3;
        int q = (c ^ r) & 7;  // XOR swizzle
        int grow = row0 + r;
        if (grow >= N) grow = 0;  // clamped rows feed only epilogue-guarded outputs
        aSrc[rr] = X + (size_t)grow * K + q * 8;
        aDst[rr] = &As[(size_t)(rr * TPB + wave * 64) * 8];
    }
    const u16* bSrc[RB];
    u16* bDst[RB];
#pragma unroll
    for (int rr = 0; rr < RB; ++rr) {
        int c = rr * TPB + t;
        int r = c >> 3;
        int q = (c ^ r) & 7;
        bSrc[rr] = Wt + (size_t)(col0 + r) * K + q * 8;
        bDst[rr] = &Bs[(size_t)(rr * TPB + wave * 64) * 8];
    }

    u32 aOff[NI][2], bOff[NJ][2];
#pragma unroll
    for (int i = 0; i < NI; ++i)
#pragma unroll
        for (int h = 0; h < 2; ++h) {
            int row = wm + i * 16 + m16;
            int qg = h * 4 + quad;
            aOff[i][h] = (u32)(((row << 3) | ((qg ^ row) & 7)) * 16);
        }
#pragma unroll
    for (int j = 0; j < NJ; ++j)
#pragma unroll
        for (int h = 0; h < 2; ++h) {
            int row = wn + j * 16 + m16;
            int qg = h * 4 + quad;
            bOff[j][h] = (u32)(((row << 3) | ((qg ^ row) & 7)) * 16);
        }
    const char* AsB = reinterpret_cast<const char*>(As);
    const char* BsB = reinterpret_cast<const char*>(Bs);

    f32x4 acc[NI][NJ] = {};

    for (int k0 = 0; k0 < K; k0 += BK) {
#pragma unroll
        for (int rr = 0; rr < RA; ++rr) {
            gl2lds16(aSrc[rr], aDst[rr]);
            aSrc[rr] += BK;
        }
#pragma unroll
        for (int rr = 0; rr < RB; ++rr) {
            gl2lds16(bSrc[rr], bDst[rr]);
            bSrc[rr] += BK;
        }
        __syncthreads();  // drains vmcnt -> LDS valid

#pragma unroll
        for (int h = 0; h < 2; ++h) {
            short8 af[NI], bf[NJ];
#pragma unroll
            for (int i = 0; i < NI; ++i)
                af[i] = *reinterpret_cast<const short8*>(AsB + aOff[i][h]);
#pragma unroll
            for (int j = 0; j < NJ; ++j)
                bf[j] = *reinterpret_cast<const short8*>(BsB + bOff[j][h]);
#pragma unroll
            for (int i = 0; i < NI; ++i)
#pragma unroll
                for (int j = 0; j < NJ; ++j)
                    acc[i][j] = __builtin_amdgcn_mfma_f32_16x16x32_bf16(af[i], bf[j], acc[i][j], 0, 0, 0);
        }
        __syncthreads();
    }

    // epilogue: C/D layout col=lane&15, row=quad*4+reg  [measured m89/m91]
#pragma unroll
    for (int i = 0; i < NI; ++i) {
#pragma unroll
        for (int r = 0; r < 4; ++r) {
            int grow = row0 + wm + i * 16 + quad * 4 + r;
            if (grow >= N) continue;
            float dv = (EPI == 0) ? dinv[grow] : 0.f;
#pragma unroll
            for (int j = 0; j < NJ; ++j) {
                int gcol = col0 + wn + j * 16 + m16;
                float v = acc[i][j][r];
                if (EPI == 0) v = dv * v;
                else          v = fmaxf(v + bias[gcol], 0.f);
                Out[(size_t)grow * F + gcol] = f2bf(v);
            }
        }
    }
}

// ---------------- standalone wrappers (serial fallback path) ----------------
template <int MODE>
__global__ __launch_bounds__(256, 4) void agg_k(
        const int* __restrict__ re, const int* __restrict__ cnt, const int* __restrict__ csr,
        const u16* __restrict__ Gin, const float* __restrict__ dinv,
        const float* __restrict__ bias, u16* __restrict__ XO, int total, int F, int lgG) {
    int gid = blockIdx.x * 256 + threadIdx.x;
    if (gid < total) agg_gid<MODE>(gid, re, cnt, csr, Gin, dinv, bias, XO, F, lgG);
}

template <int BN, int TPB, int EPI>
__global__ __launch_bounds__(TPB) void gemm_k(
        const u16* X, const u16* __restrict__ Wt, const float* __restrict__ dinv,
        const float* __restrict__ bias, u16* Out, int N, int K, int F, int nx) {
    __shared__ u16 As[128 * 64];
    __shared__ u16 Bs[BN * 64];
    int tile = blockIdx.x;
    gemm_tile<BN, TPB, EPI>(As, Bs, tile / nx, tile % nx, threadIdx.x,
                            X, Wt, dinv, bias, Out, N, K, F);
}

__global__ __launch_bounds__(256, 4) void l5_k(
        const int* __restrict__ re, const int* __restrict__ cnt, const int* __restrict__ csr,
        const u16* __restrict__ Gc, const float* __restrict__ dinv,
        const float* __restrict__ b4, const float* __restrict__ W5,
        float* __restrict__ g5, int total) {
    int gid = blockIdx.x * 256 + threadIdx.x;
    if (gid < total) l5_gid(gid, re, cnt, csr, Gc, dinv, b4, W5, g5);
}

__global__ void agg5_k(const int* __restrict__ re, const int* __restrict__ cnt,
                       const int* __restrict__ csr, const float* __restrict__ g5,
                       const float* __restrict__ dinv, const float* __restrict__ b5,
                       float* __restrict__ out, int N) {
    int i = blockIdx.x * blockDim.x + threadIdx.x;
    if (i < N) agg5_gid(i, re, cnt, csr, g5, dinv, b5, out);
}

// ---------------- cooperative mega-kernel: 9 layer dispatches -> 1 node ----------------
// R6 lesson: __launch_bounds__(512,6) capped unified VGPR+AGPR at ~85 but gemm_tile
// needs ~124 (60 VGPR + 64 AGPR acc) -> accumulator spilled to scratch every K-step
// (WRITE_SIZE 2.26 GB, 4.6x slowdown). Fix: no min-waves clamp (allocator takes what
// it needs, no spills); occupancy becomes LDS-bound (48 KB -> 3 blocks/CU) and the
// cooperative grid is sized at runtime from hipOccupancyMaxActiveBlocksPerMultiprocessor.
struct MegaP {
    const int* rstart; const int* cnt; const int* csr;
    const u16* Y; u16* Z; u16* Gc; u16* XA; u16* XB;
    const float* dinv;
    const u16* Wt0; const u16* Wt1; const u16* Wt2; const u16* Wt3;
    const float* bias1024; const float* bias512; const float* bias256;
    const float* bias64; const float* bias1;
    const float* W5;
    float* g5; float* out;
    int N; int ny;
};

__global__ __launch_bounds__(512) void mega_kernel(MegaP P) {
    __shared__ u16 As[128 * 64];   // 16 KB
    __shared__ u16 Bs[256 * 64];   // 32 KB
    cg::grid_group grid = cg::this_grid();
    const int t = threadIdx.x;
    const int nb = (int)gridDim.x;
    const int tstride = nb * 512;
    const int N = P.N, ny = P.ny;

    // s0: layer-1 pre-agg  Y -> Z   (F=128, 8 thr/node)
    for (int gid = blockIdx.x * 512 + t, tot = N << 3; gid < tot; gid += tstride)
        agg_gid<0>(gid, P.rstart, P.cnt, P.csr, P.Y, P.dinv, nullptr, P.Z, 128, 3);
    grid.sync();

    // s1: gemm1  Z @ W1 -> XA  (K=128, F=1024, EPI=1)
    for (int tile = blockIdx.x, nt = ny * 4; tile < nt; tile += nb) {
        gemm_tile<256, 512, 1>(As, Bs, tile >> 2, tile & 3, t,
                               P.Z, P.Wt0, P.dinv, P.bias1024, P.XA, N, 128, 1024);
        __syncthreads();
    }
    grid.sync();

    // s2: gemm2  XA @ W2 -> Gc512  (K=1024, F=512, EPI=0)
    for (int tile = blockIdx.x, nt = ny * 2; tile < nt; tile += nb) {
        gemm_tile<256, 512, 0>(As, Bs, tile >> 1, tile & 1, t,
                               P.XA, P.Wt1, P.dinv, P.bias512, P.Gc, N, 1024, 512);
        __syncthreads();
    }
    grid.sync();

    // s3: agg2  Gc512 -> XB  (F=512, 32 thr/node, bias b2 + relu)
    for (int gid = blockIdx.x * 512 + t, tot = N << 5; gid < tot; gid += tstride)
        agg_gid<1>(gid, P.rstart, P.cnt, P.csr, P.Gc, P.dinv, P.bias512, P.XB, 512, 5);
    grid.sync();

    // s4: gemm3  XB @ W3 -> Gc256  (K=512, F=256, EPI=0)
    for (int tile = blockIdx.x; tile < ny; tile += nb) {
        gemm_tile<256, 512, 0>(As, Bs, tile, 0, t,
                               P.XB, P.Wt2, P.dinv, P.bias256, P.Gc, N, 512, 256);
        __syncthreads();
    }
    grid.sync();

    // s5: agg3  Gc256 -> XA  (F=256, 16 thr/node, bias b3 + relu)
    for (int gid = blockIdx.x * 512 + t, tot = N << 4; gid < tot; gid += tstride)
        agg_gid<1>(gid, P.rstart, P.cnt, P.csr, P.Gc, P.dinv, P.bias256, P.XA, 256, 4);
    grid.sync();

    // s6: gemm4  XA @ W4 -> Gc64  (K=256, F=64, EPI=0)
    for (int tile = blockIdx.x; tile < ny; tile += nb) {
        gemm_tile<64, 512, 0>(As, Bs, tile, 0, t,
                              P.XA, P.Wt3, P.dinv, P.bias64, P.Gc, N, 256, 64);
        __syncthreads();
    }
    grid.sync();

    // s7: fused layer-4 agg + layer-5 dot  Gc64 -> g5
    for (int gid = blockIdx.x * 512 + t, tot = N << 2; gid < tot; gid += tstride)
        l5_gid(gid, P.rstart, P.cnt, P.csr, P.Gc, P.dinv, P.bias64, P.W5, P.g5);
    grid.sync();

    // s8: layer-5 aggregation  g5 -> out
    for (int i = blockIdx.x * 512 + t; i < N; i += tstride)
        agg5_gid(i, P.rstart, P.cnt, P.csr, P.g5, P.dinv, P.bias1, P.out);
}

// ---------------- launch ----------------

static inline size_t align_up(size_t x) { return (x + 255) & ~(size_t)255; }

extern "C" void kernel_launch(void* const* d_in, const int* in_sizes, int n_in,
                              void* d_out, int out_size, void* d_ws, size_t ws_size,
                              hipStream_t stream) {
    const float* x  = (const float*)d_in[0];
    const int*   ei = (const int*)d_in[1];
    const int E = in_sizes[1] / 2;
    const int N = in_sizes[0] / N_NODES_DIM0;
    const int* src = ei;
    const int* dst = ei + E;

    const float* W[5] = {(const float*)d_in[2], (const float*)d_in[4], (const float*)d_in[6],
                         (const float*)d_in[8], (const float*)d_in[10]};
    const float* B[5] = {(const float*)d_in[3], (const float*)d_in[5], (const float*)d_in[7],
                         (const float*)d_in[9], (const float*)d_in[11]};

    const int Ks[4] = {128, 1024, 512, 256};
    const int Fs[4] = {1024, 512, 256, 64};

    // workspace carve — peak ~209 MB
    char* w = (char*)d_ws;
    size_t off = 0;
    float* dinv    = (float*)(w + off); off += align_up((size_t)N * 4);
    float* g5      = (float*)(w + off); off += align_up((size_t)N * 4);
    int*   cnt     = (int*)(w + off);   off += align_up((size_t)(N + 1) * 4);  // cnt[N] = cursor
    int*   rstart  = (int*)(w + off);   off += align_up((size_t)N * 4);        // bump ptr -> row end
    int*   csr_src = (int*)(w + off);   off += align_up((size_t)E * 4);        // 1.6 MB
    u16* WtBase = (u16*)(w + off);
    u16* Wt[4];
    {
        size_t cum = 0;
        for (int l = 0; l < 4; ++l) {
            Wt[l] = WtBase + cum;
            cum += (size_t)Ks[l] * Fs[l];
        }
        off += align_up(cum * 2);
    }
    char* REG = w + off;               off += align_up((size_t)N * 512 * 2);    // 51.2 MB
    u16* Y  = (u16*)REG;
    u16* Z  = (u16*)(REG + align_up((size_t)N * 128 * 2));
    u16* Gc = (u16*)REG;               // 512/256/64-wide GEMM outputs (sequenced reuse)
    u16* XA = (u16*)(w + off);         off += align_up((size_t)N * 1024 * 2);   // 102.4 MB
    u16* XB = (u16*)(w + off);         off += align_up((size_t)N * 512 * 2);    // 51.2 MB
    (void)ws_size;

    // ---- setup: 4 nodes ----
    hipMemsetAsync(cnt, 0, (size_t)(N + 1) * 4, stream);
    {
        int histB = (E + 255) / 256;
        hist_wt_kernel<<<histB + 784, 256, 0, stream>>>(dst, cnt, E, histB,
                                                        W[0], W[1], W[2], W[3], WtBase);
    }
    alloc_kernel<<<(N + 255) / 256, 256, 0, stream>>>(cnt, rstart, dinv, &cnt[N], N);
    {
        int fillB = (E + 255) / 256;
        int yB = (N * 32 + 255) / 256;
        fill_y_kernel<<<fillB + yB, 256, 0, stream>>>(src, dst, rstart, csr_src, E, fillB,
                                                      x, dinv, Y, N);
    }

    const int ny = (N + 127) / 128;

    // ---- all 9 layer stages: one cooperative node ----
    MegaP P;
    P.rstart = rstart; P.cnt = cnt; P.csr = csr_src;
    P.Y = Y; P.Z = Z; P.Gc = Gc; P.XA = XA; P.XB = XB;
    P.dinv = dinv;
    P.Wt0 = Wt[0]; P.Wt1 = Wt[1]; P.Wt2 = Wt[2]; P.Wt3 = Wt[3];
    P.bias1024 = B[0]; P.bias512 = B[1]; P.bias256 = B[2]; P.bias64 = B[3]; P.bias1 = B[4];
    P.W5 = W[4];
    P.g5 = g5; P.out = (float*)d_out;
    P.N = N; P.ny = ny;

    int occ = 0;
    hipError_t qerr = hipOccupancyMaxActiveBlocksPerMultiprocessor(
        &occ, (const void*)mega_kernel, 512, 0);
    hipError_t err = hipErrorUnknown;
    if (qerr == hipSuccess && occ >= 1) {
        int grid = occ * 256;
        void* args[] = { &P };
        err = hipLaunchCooperativeKernel((const void*)mega_kernel,
                                         dim3(grid), dim3(512), args, 0, stream);
    }
    if (err != hipSuccess) {
        (void)hipGetLastError();  // clear sticky error; serial fallback (R4 pipeline)
        agg_k<0><<<(N * 8 + 255) / 256, 256, 0, stream>>>(
            rstart, cnt, csr_src, Y, dinv, nullptr, Z, N * 8, 128, 3);
        gemm_k<256, 512, 1><<<ny * 4, 512, 0, stream>>>(Z, Wt[0], dinv, B[0], XA,
                                                        N, 128, 1024, 4);
        gemm_k<256, 512, 0><<<ny * 2, 512, 0, stream>>>(XA, Wt[1], dinv, B[1], Gc,
                                                        N, 1024, 512, 2);
        agg_k<1><<<(N * 32 + 255) / 256, 256, 0, stream>>>(
            rstart, cnt, csr_src, Gc, dinv, B[1], XB, N * 32, 512, 5);
        gemm_k<256, 512, 0><<<ny, 512, 0, stream>>>(XB, Wt[2], dinv, B[2], Gc,
                                                    N, 512, 256, 1);
        agg_k<1><<<(N * 16 + 255) / 256, 256, 0, stream>>>(
            rstart, cnt, csr_src, Gc, dinv, B[2], XA, N * 16, 256, 4);
        gemm_k<64, 512, 0><<<ny, 512, 0, stream>>>(XA, Wt[3], dinv, B[3], Gc,
                                                   N, 256, 64, 1);
        l5_k<<<(N * 4 + 255) / 256, 256, 0, stream>>>(rstart, cnt, csr_src, Gc, dinv,
                                                      B[3], W[4], g5, N * 4);
        agg5_k<<<(N + 255) / 256, 256, 0, stream>>>(rstart, cnt, csr_src, g5, dinv,
                                                    B[4], (float*)d_out, N);
    }
}